// Round 1
// baseline (3192.938 us; speedup 1.0000x reference)
//
#include <hip/hip_runtime.h>
#include <stdint.h>

#define BATCH 2048
#define IN_DIM 1024
#define HID 32768
#define TOPK 32

// ---------------- Kernel 1: encode GEMM + bias + relu ----------------
// h[m, n] = relu( sum_k x[m,k] * W_enc[n,k] + b_enc[n] )
// BM=64 (batch), BN=128 (hidden), BK=16; 256 threads; 4x8 micro-tile.
#define BM 64
#define BN 128
#define BK 16
#define LDA 68   // 68*4 = 272 bytes, multiple of 16 -> aligned ds_read_b128; 68%32=4 breaks bank aliasing
#define LDB 132  // 132*4 = 528 bytes, multiple of 16

__global__ __launch_bounds__(256) void encode_gemm(
    const float* __restrict__ x, const float* __restrict__ We,
    const float* __restrict__ be, float* __restrict__ h)
{
    __shared__ __align__(16) float As[BK][LDA];
    __shared__ __align__(16) float Bs[BK][LDB];
    const int n0 = blockIdx.x * BN;
    const int m0 = blockIdx.y * BM;
    const int t  = threadIdx.x;
    const int tx = t & 15;          // 16 n-groups of 8
    const int ty = t >> 4;          // 16 m-groups of 4
    const int ar = t >> 2;          // 0..63 staging row
    const int ak = (t & 3) * 4;     // 0,4,8,12 staging k-offset

    const float* ap  = x  + (size_t)(m0 + ar) * IN_DIM + ak;
    const float* bp0 = We + (size_t)(n0 + ar) * IN_DIM + ak;
    const float* bp1 = We + (size_t)(n0 + 64 + ar) * IN_DIM + ak;

    float acc[4][8] = {};

    for (int kt = 0; kt < IN_DIM; kt += BK) {
        float4 av  = *(const float4*)(ap  + kt);
        float4 bv0 = *(const float4*)(bp0 + kt);
        float4 bv1 = *(const float4*)(bp1 + kt);
        __syncthreads();
        As[ak+0][ar] = av.x;  As[ak+1][ar] = av.y;  As[ak+2][ar] = av.z;  As[ak+3][ar] = av.w;
        Bs[ak+0][ar] = bv0.x; Bs[ak+1][ar] = bv0.y; Bs[ak+2][ar] = bv0.z; Bs[ak+3][ar] = bv0.w;
        Bs[ak+0][ar+64] = bv1.x; Bs[ak+1][ar+64] = bv1.y; Bs[ak+2][ar+64] = bv1.z; Bs[ak+3][ar+64] = bv1.w;
        __syncthreads();
        #pragma unroll
        for (int kk = 0; kk < BK; kk++) {
            float a_[4], b_[8];
            *(float4*)a_     = *(const float4*)&As[kk][ty*4];
            *(float4*)b_     = *(const float4*)&Bs[kk][tx*8];
            *(float4*)(b_+4) = *(const float4*)&Bs[kk][tx*8+4];
            #pragma unroll
            for (int i = 0; i < 4; i++)
                #pragma unroll
                for (int j = 0; j < 8; j++)
                    acc[i][j] += a_[i] * b_[j];
        }
    }

    float be_[8];
    *(float4*)be_     = *(const float4*)&be[n0 + tx*8];
    *(float4*)(be_+4) = *(const float4*)&be[n0 + tx*8 + 4];
    #pragma unroll
    for (int i = 0; i < 4; i++) {
        float o[8];
        #pragma unroll
        for (int j = 0; j < 8; j++) {
            float v = acc[i][j] + be_[j];
            o[j] = v > 0.0f ? v : 0.0f;
        }
        float* dst = h + (size_t)(m0 + ty*4 + i) * HID + n0 + tx*8;
        *(float4*)dst     = *(const float4*)o;
        *(float4*)(dst+4) = *(const float4*)(o+4);
    }
}

// ---------------- Kernel 2: exact per-row top-32 + mask ----------------
// One block (1024 threads) per row. Values are relu'd (>=0) so float bits are
// monotonic as uint32. Bitwise binary search finds the exact 32nd-largest
// value T; ties at T broken lowest-index-first (jax.lax.top_k semantics).
__global__ __launch_bounds__(1024) void topk_mask(
    float* __restrict__ h, int* __restrict__ wIdx, float* __restrict__ wVal)
{
    const int row = blockIdx.x;
    const int tid = threadIdx.x;
    float* hrow = h + (size_t)row * HID;

    uint32_t u[32];
    #pragma unroll
    for (int i = 0; i < 32; i++)
        u[i] = __float_as_uint(hrow[tid + (i << 10)]);   // coalesced, stride 1024

    __shared__ int s_wave[16];
    __shared__ int s_total;
    __shared__ int s_cgt;
    __shared__ int s_ceq;
    __shared__ int s_keep;
    __shared__ int s_eq[64];

    uint32_t lo = 0;
    for (int bit = 30; bit >= 0; bit--) {   // sign bit never set (relu)
        uint32_t cand = lo | (1u << bit);
        int local = 0;
        #pragma unroll
        for (int i = 0; i < 32; i++) local += (u[i] >= cand) ? 1 : 0;
        #pragma unroll
        for (int off = 32; off > 0; off >>= 1) local += __shfl_down(local, off);
        if ((tid & 63) == 0) s_wave[tid >> 6] = local;
        __syncthreads();
        if (tid == 0) {
            int tot = 0;
            #pragma unroll
            for (int w = 0; w < 16; w++) tot += s_wave[w];
            s_total = tot;
        }
        __syncthreads();
        if (s_total >= TOPK) lo = cand;
        __syncthreads();   // protect s_wave/s_total reuse next iteration
    }
    const uint32_t T = lo;   // exact bit pattern of the 32nd largest value

    if (tid == 0) { s_cgt = 0; s_ceq = 0; }
    __syncthreads();

    // compact strictly-greater entries (count <= 31 by construction)
    #pragma unroll
    for (int i = 0; i < 32; i++) {
        int idx = tid + (i << 10);
        if (u[i] > T) {
            int p = atomicAdd(&s_cgt, 1);
            wIdx[row * TOPK + p] = idx;
            wVal[row * TOPK + p] = __uint_as_float(u[i]);
        } else if (T != 0u && u[i] == T) {
            int p = atomicAdd(&s_ceq, 1);
            if (p < 64) s_eq[p] = idx;
        }
    }
    __syncthreads();

    if (tid == 0) {
        int c = s_cgt;
        int r = TOPK - c;           // how many ties to keep, >= 1
        if (T == 0u) {
            // fewer than 32 positive activations: remaining slots are zeros
            for (int q = 0; q < r; q++) {
                wIdx[row * TOPK + c + q] = 0;
                wVal[row * TOPK + c + q] = 0.0f;
            }
            s_keep = 0;
        } else {
            int e = s_ceq; if (e > 64) e = 64;
            // insertion-sort tie indices ascending: keep lowest indices first
            for (int a = 1; a < e; a++) {
                int key = s_eq[a]; int b2 = a - 1;
                while (b2 >= 0 && s_eq[b2] > key) { s_eq[b2+1] = s_eq[b2]; b2--; }
                s_eq[b2+1] = key;
            }
            if (r > e) r = e;       // paranoia, cannot happen
            for (int q = 0; q < r; q++) {
                wIdx[row * TOPK + c + q] = s_eq[q];
                wVal[row * TOPK + c + q] = __uint_as_float(T);
            }
            for (int q = c + r; q < TOPK; q++) {   // paranoia fill
                wIdx[row * TOPK + q] = 0; wVal[row * TOPK + q] = 0.0f;
            }
            s_keep = r;
        }
    }
    __syncthreads();
    const int r2 = s_keep;

    // write back masked h (values already in registers)
    #pragma unroll
    for (int i = 0; i < 32; i++) {
        int idx = tid + (i << 10);
        uint32_t uu = u[i];
        bool keep = uu > T;
        if (!keep && T != 0u && uu == T) {
            for (int q = 0; q < r2; q++) keep = keep || (s_eq[q] == idx);
        }
        hrow[idx] = keep ? __uint_as_float(uu) : 0.0f;
    }
}

// ---------------- Kernel 3: sparse decode ----------------
// x_hat[b, i] = b_dec[i] + sum_k val[b,k] * W_dec[i, idx[b,k]]
// One block per output dim i; the contiguous 128KB W_dec row is staged
// through LDS in 64KB chunks so the per-index gathers hit LDS, not
// strided HBM columns.
#define DCHUNK 16384   // floats per chunk = 64 KB

__global__ __launch_bounds__(256) void decode_sparse(
    const float* __restrict__ Wd, const float* __restrict__ bd,
    const int* __restrict__ wIdx, const float* __restrict__ wVal,
    float* __restrict__ xhat)
{
    extern __shared__ float lds[];
    const int i = blockIdx.x;
    const int t = threadIdx.x;
    const float* wrow = Wd + (size_t)i * HID;
    const float bias = bd[i];
    float acc[8];
    #pragma unroll
    for (int q = 0; q < 8; q++) acc[q] = bias;

    for (int ch = 0; ch < HID / DCHUNK; ch++) {
        __syncthreads();
        const float4* src = (const float4*)(wrow + ch * DCHUNK);
        #pragma unroll
        for (int j = 0; j < DCHUNK / 4 / 256; j++)
            ((float4*)lds)[t + j * 256] = src[t + j * 256];
        __syncthreads();
        const uint32_t base = (uint32_t)(ch * DCHUNK);
        #pragma unroll
        for (int q = 0; q < 8; q++) {
            const int b = t + (q << 8);
            const int*   ip = wIdx + b * TOPK;
            const float* vp = wVal + b * TOPK;
            #pragma unroll 4
            for (int k = 0; k < TOPK; k++) {
                uint32_t off = (uint32_t)ip[k] - base;
                if (off < (uint32_t)DCHUNK)
                    acc[q] += vp[k] * lds[off];
            }
        }
    }
    #pragma unroll
    for (int q = 0; q < 8; q++) {
        const int b = t + (q << 8);
        xhat[(size_t)b * IN_DIM + i] = acc[q];
    }
}

extern "C" void kernel_launch(void* const* d_in, const int* in_sizes, int n_in,
                              void* d_out, int out_size, void* d_ws, size_t ws_size,
                              hipStream_t stream)
{
    const float* x  = (const float*)d_in[0];
    const float* We = (const float*)d_in[1];
    const float* be = (const float*)d_in[2];
    const float* Wd = (const float*)d_in[3];
    const float* bd = (const float*)d_in[4];

    float* xhat = (float*)d_out;                                   // [2048, 1024]
    float* h    = (float*)d_out + (size_t)BATCH * IN_DIM;          // [2048, 32768]

    int*   wIdx = (int*)d_ws;                                      // [2048][32]
    float* wVal = (float*)((char*)d_ws + sizeof(int) * BATCH * TOPK);

    dim3 g1(HID / BN, BATCH / BM);
    encode_gemm<<<g1, 256, 0, stream>>>(x, We, be, h);
    topk_mask<<<BATCH, 1024, 0, stream>>>(h, wIdx, wVal);
    decode_sparse<<<IN_DIM, 256, 65536, stream>>>(Wd, bd, wIdx, wVal, xhat);
}

// Round 2
// 1436.876 us; speedup vs baseline: 2.2221x; 2.2221x over previous
//
#include <hip/hip_runtime.h>
#include <stdint.h>

#define BATCH 2048
#define IN_DIM 1024
#define HID 32768
#define TOPK 32

typedef __attribute__((ext_vector_type(8))) short short8;
typedef __attribute__((ext_vector_type(4))) float f32x4;

// =====================================================================
// FAST PATH
// =====================================================================

// ---------- fp32 -> bf16 (RNE), n4 = element count / 4 ----------
__global__ __launch_bounds__(256) void to_bf16(const float* __restrict__ src,
                                               ushort* __restrict__ dst, int n4)
{
    int i = blockIdx.x * 256 + threadIdx.x;
    if (i >= n4) return;
    float4 v = ((const float4*)src)[i];
    ushort4 o;
    uint32_t u;
    u = __float_as_uint(v.x); o.x = (ushort)((u + 0x7FFFu + ((u >> 16) & 1u)) >> 16);
    u = __float_as_uint(v.y); o.y = (ushort)((u + 0x7FFFu + ((u >> 16) & 1u)) >> 16);
    u = __float_as_uint(v.z); o.z = (ushort)((u + 0x7FFFu + ((u >> 16) & 1u)) >> 16);
    u = __float_as_uint(v.w); o.w = (ushort)((u + 0x7FFFu + ((u >> 16) & 1u)) >> 16);
    ((ushort4*)dst)[i] = o;
}

// ---------- bf16 MFMA encode: approx = relu(x @ We^T + be) ----------
// 128x128 tile, BK=32, 4 waves; m97 structure: global_load_lds(16B) staging,
// 8 ds_read_b128 + 16 mfma_f32_16x16x32_bf16 per K-step.
__global__ __launch_bounds__(256) void encode_mfma(
    const ushort* __restrict__ xb, const ushort* __restrict__ wb,
    const float* __restrict__ be, float* __restrict__ out)
{
    __shared__ __align__(16) ushort As[128 * 32];   // [row][k], 64B rows, no pad
    __shared__ __align__(16) ushort Bs[128 * 32];
    const int t    = threadIdx.x;
    const int wave = t >> 6;
    const int lane = t & 63;
    const int m0 = blockIdx.y * 128;
    const int n0 = blockIdx.x * 128;
    const int wm = (wave >> 1) * 64;
    const int wn = (wave & 1) * 64;

    // staging: lane L of (wave, q) -> row wave*32 + q*16 + (L>>2), kchunk (L&3)*8
    const int srow = lane >> 2;
    const int scol = (lane & 3) * 8;
    const ushort* gA0 = xb + (size_t)(m0 + wave * 32 + srow) * IN_DIM + scol;
    const ushort* gA1 = gA0 + 16 * IN_DIM;
    const ushort* gB0 = wb + (size_t)(n0 + wave * 32 + srow) * IN_DIM + scol;
    const ushort* gB1 = gB0 + 16 * IN_DIM;
    ushort* lA0 = &As[(wave * 32 + 0)  * 32];
    ushort* lA1 = &As[(wave * 32 + 16) * 32];
    ushort* lB0 = &Bs[(wave * 32 + 0)  * 32];
    ushort* lB1 = &Bs[(wave * 32 + 16) * 32];

    f32x4 acc[4][4];
    #pragma unroll
    for (int i = 0; i < 4; i++)
        #pragma unroll
        for (int j = 0; j < 4; j++) acc[i][j] = 0.f;

    const int fr   = lane & 15;   // m (A) / n (B) within 16-tile
    const int quad = lane >> 4;   // k-chunk selector

    for (int kt = 0; kt < IN_DIM; kt += 32) {
        __builtin_amdgcn_global_load_lds((const __attribute__((address_space(1))) void*)(gA0 + kt),
                                         (__attribute__((address_space(3))) void*)lA0, 16, 0, 0);
        __builtin_amdgcn_global_load_lds((const __attribute__((address_space(1))) void*)(gA1 + kt),
                                         (__attribute__((address_space(3))) void*)lA1, 16, 0, 0);
        __builtin_amdgcn_global_load_lds((const __attribute__((address_space(1))) void*)(gB0 + kt),
                                         (__attribute__((address_space(3))) void*)lB0, 16, 0, 0);
        __builtin_amdgcn_global_load_lds((const __attribute__((address_space(1))) void*)(gB1 + kt),
                                         (__attribute__((address_space(3))) void*)lB1, 16, 0, 0);
        __syncthreads();   // drains vmcnt -> staged data visible
        short8 af[4], bf[4];
        #pragma unroll
        for (int i = 0; i < 4; i++) {
            af[i] = *(const short8*)&As[(wm + i * 16 + fr) * 32 + quad * 8];
            bf[i] = *(const short8*)&Bs[(wn + i * 16 + fr) * 32 + quad * 8];
        }
        #pragma unroll
        for (int mt = 0; mt < 4; mt++)
            #pragma unroll
            for (int nt = 0; nt < 4; nt++)
                acc[mt][nt] = __builtin_amdgcn_mfma_f32_16x16x32_bf16(
                    af[mt], bf[nt], acc[mt][nt], 0, 0, 0);
        __syncthreads();   // protect LDS before next staging
    }

    // epilogue: C/D layout col(n)=lane&15, row(m)=quad*4+reg  [m89/m91-verified]
    #pragma unroll
    for (int nt = 0; nt < 4; nt++) {
        const int n = n0 + wn + nt * 16 + fr;
        const float bias = be[n];
        #pragma unroll
        for (int mt = 0; mt < 4; mt++) {
            #pragma unroll
            for (int r = 0; r < 4; r++) {
                const int m = m0 + wm + mt * 16 + quad * 4 + r;
                float v = acc[mt][nt][r] + bias;
                out[(size_t)m * HID + n] = v > 0.f ? v : 0.f;
            }
        }
    }
}

// ---------- topk + exact fp32 re-rank + final h write ----------
// hbuf holds relu'd approx scores on entry; on exit it holds the final sparse h.
// wIdx/wVal are TRANSPOSED: [TOPK][BATCH] for coalesced decode loads.
#define DELTA 0.0625f
#define MAXC 512

__global__ __launch_bounds__(1024) void topk_rerank(
    float* __restrict__ hbuf,
    const float* __restrict__ x, const float* __restrict__ We,
    const float* __restrict__ be,
    int* __restrict__ wIdx, float* __restrict__ wVal)
{
    const int row = blockIdx.x;
    const int tid = threadIdx.x;
    float* hrow = hbuf + (size_t)row * HID;

    float a[32];
    #pragma unroll
    for (int i = 0; i < 32; i++) a[i] = hrow[tid + (i << 10)];

    __shared__ int   hist[256];
    __shared__ float s_thresh;
    __shared__ int   c_n;
    __shared__ int   c_idx[MAXC];
    __shared__ float c_val[MAXC];
    __shared__ float xs[IN_DIM];
    __shared__ int   win_i[TOPK];
    __shared__ float win_v[TOPK];

    if (tid < 256) hist[tid] = 0;
    xs[tid] = x[(size_t)row * IN_DIM + tid];
    if (tid == 0) c_n = 0;
    __syncthreads();

    #pragma unroll
    for (int i = 0; i < 32; i++) {
        if (a[i] > 0.f) {
            int b = (int)(a[i] * 128.f); if (b > 255) b = 255;
            atomicAdd(&hist[b], 1);
        }
    }
    __syncthreads();

    if (tid == 0) {
        int acc = 0, b = 255;
        for (; b >= 0; b--) { acc += hist[b]; if (acc >= TOPK) break; }
        // bucketLow <= approxT32, so bucketLow - DELTA <= approxT32 - DELTA
        s_thresh = (b >= 0) ? ((float)b * (1.f / 128.f) - DELTA) : 0.f;
    }
    __syncthreads();
    const float th = s_thresh;

    #pragma unroll
    for (int i = 0; i < 32; i++) {
        if (a[i] > 0.f && a[i] >= th) {
            int p = atomicAdd(&c_n, 1);
            if (p < MAXC) c_idx[p] = tid + (i << 10);
        }
    }
    __syncthreads();
    const int nc = c_n < MAXC ? c_n : MAXC;

    // exact fp32 recompute, one wave per candidate
    const int wv = tid >> 6, ln = tid & 63;
    for (int c = wv; c < nc; c += 16) {
        const float4* wr = (const float4*)(We + (size_t)c_idx[c] * IN_DIM);
        const float4* xv = (const float4*)xs;
        float s = 0.f;
        #pragma unroll
        for (int q = 0; q < 4; q++) {
            float4 w4 = wr[ln * 4 + q];
            float4 x4 = xv[ln * 4 + q];
            s += w4.x * x4.x + w4.y * x4.y + w4.z * x4.z + w4.w * x4.w;
        }
        #pragma unroll
        for (int off = 32; off > 0; off >>= 1) s += __shfl_down(s, off);
        if (ln == 0) {
            s += be[c_idx[c]];
            c_val[c] = s > 0.f ? s : 0.f;
        }
    }
    if (tid < TOPK) {   // prefill outputs (covers nc < 32 case)
        win_i[tid] = -1; win_v[tid] = 0.f;
        wIdx[tid * BATCH + row] = 0;
        wVal[tid * BATCH + row] = 0.f;
    }
    __syncthreads();

    // parallel exact ranking, ties -> lowest index (jax.lax.top_k semantics)
    if (tid < nc) {
        const float v = c_val[tid];
        const int  id = c_idx[tid];
        int r = 0;
        for (int j = 0; j < nc; j++) {
            float vj = c_val[j]; int ij = c_idx[j];
            r += (vj > v) || (vj == v && ij < id) ? 1 : 0;
        }
        if (r < TOPK) {
            win_i[r] = id; win_v[r] = v;
            wIdx[r * BATCH + row] = id;
            wVal[r * BATCH + row] = v;
        }
    }
    __syncthreads();

    // zero the row, then scatter the 32 exact winners
    float4* h4 = (float4*)hrow;
    float4 z; z.x = z.y = z.z = z.w = 0.f;
    #pragma unroll
    for (int i = 0; i < 8; i++) h4[tid + (i << 10)] = z;
    __syncthreads();
    if (tid < TOPK && win_i[tid] >= 0)
        hrow[win_i[tid]] = win_v[tid];
}

// ---------- sparse decode (transposed lists) ----------
// x_hat[b,i] = bd[i] + sum_k wVal[k][b] * Wd[i, wIdx[k][b]]
#define DCHUNK 16384   // floats per LDS chunk = 64 KB

__global__ __launch_bounds__(256) void decode_sparse(
    const float* __restrict__ Wd, const float* __restrict__ bd,
    const int* __restrict__ wIdx, const float* __restrict__ wVal,
    float* __restrict__ xhat)
{
    extern __shared__ float lds[];
    const int i = blockIdx.x;
    const int t = threadIdx.x;
    const float* wrow = Wd + (size_t)i * HID;
    const float bias = bd[i];
    float acc[8];
    #pragma unroll
    for (int q = 0; q < 8; q++) acc[q] = bias;

    for (int ch = 0; ch < HID / DCHUNK; ch++) {
        __syncthreads();
        const float4* src = (const float4*)(wrow + ch * DCHUNK);
        #pragma unroll
        for (int j = 0; j < DCHUNK / 4 / 256; j++)
            ((float4*)lds)[t + j * 256] = src[t + j * 256];
        __syncthreads();
        const uint32_t base = (uint32_t)(ch * DCHUNK);
        #pragma unroll
        for (int q = 0; q < 8; q++) {
            const int b = t + (q << 8);
            #pragma unroll 4
            for (int k = 0; k < TOPK; k++) {
                uint32_t off = (uint32_t)wIdx[(k << 11) + b] - base;  // coalesced
                if (off < (uint32_t)DCHUNK)
                    acc[q] += wVal[(k << 11) + b] * lds[off];
            }
        }
    }
    #pragma unroll
    for (int q = 0; q < 8; q++) {
        const int b = t + (q << 8);
        xhat[(size_t)b * IN_DIM + i] = acc[q];
    }
}

// =====================================================================
// FALLBACK PATH (round-1, passes) — used only if ws_size is too small
// =====================================================================
#define BM 64
#define BN 128
#define BK 16
#define LDA 68
#define LDB 132

__global__ __launch_bounds__(256) void encode_gemm(
    const float* __restrict__ x, const float* __restrict__ We,
    const float* __restrict__ be, float* __restrict__ h)
{
    __shared__ __align__(16) float As[BK][LDA];
    __shared__ __align__(16) float Bs[BK][LDB];
    const int n0 = blockIdx.x * BN;
    const int m0 = blockIdx.y * BM;
    const int t  = threadIdx.x;
    const int tx = t & 15;
    const int ty = t >> 4;
    const int ar = t >> 2;
    const int ak = (t & 3) * 4;

    const float* ap  = x  + (size_t)(m0 + ar) * IN_DIM + ak;
    const float* bp0 = We + (size_t)(n0 + ar) * IN_DIM + ak;
    const float* bp1 = We + (size_t)(n0 + 64 + ar) * IN_DIM + ak;

    float acc[4][8] = {};
    for (int kt = 0; kt < IN_DIM; kt += BK) {
        float4 av  = *(const float4*)(ap  + kt);
        float4 bv0 = *(const float4*)(bp0 + kt);
        float4 bv1 = *(const float4*)(bp1 + kt);
        __syncthreads();
        As[ak+0][ar] = av.x;  As[ak+1][ar] = av.y;  As[ak+2][ar] = av.z;  As[ak+3][ar] = av.w;
        Bs[ak+0][ar] = bv0.x; Bs[ak+1][ar] = bv0.y; Bs[ak+2][ar] = bv0.z; Bs[ak+3][ar] = bv0.w;
        Bs[ak+0][ar+64] = bv1.x; Bs[ak+1][ar+64] = bv1.y; Bs[ak+2][ar+64] = bv1.z; Bs[ak+3][ar+64] = bv1.w;
        __syncthreads();
        #pragma unroll
        for (int kk = 0; kk < BK; kk++) {
            float a_[4], b_[8];
            *(float4*)a_     = *(const float4*)&As[kk][ty*4];
            *(float4*)b_     = *(const float4*)&Bs[kk][tx*8];
            *(float4*)(b_+4) = *(const float4*)&Bs[kk][tx*8+4];
            #pragma unroll
            for (int i = 0; i < 4; i++)
                #pragma unroll
                for (int j = 0; j < 8; j++)
                    acc[i][j] += a_[i] * b_[j];
        }
    }
    float be_[8];
    *(float4*)be_     = *(const float4*)&be[n0 + tx*8];
    *(float4*)(be_+4) = *(const float4*)&be[n0 + tx*8 + 4];
    #pragma unroll
    for (int i = 0; i < 4; i++) {
        float o[8];
        #pragma unroll
        for (int j = 0; j < 8; j++) {
            float v = acc[i][j] + be_[j];
            o[j] = v > 0.0f ? v : 0.0f;
        }
        float* dst = h + (size_t)(m0 + ty*4 + i) * HID + n0 + tx*8;
        *(float4*)dst     = *(const float4*)o;
        *(float4*)(dst+4) = *(const float4*)(o+4);
    }
}

__global__ __launch_bounds__(1024) void topk_mask(
    float* __restrict__ h, int* __restrict__ wIdx, float* __restrict__ wVal)
{
    const int row = blockIdx.x;
    const int tid = threadIdx.x;
    float* hrow = h + (size_t)row * HID;

    uint32_t u[32];
    #pragma unroll
    for (int i = 0; i < 32; i++)
        u[i] = __float_as_uint(hrow[tid + (i << 10)]);

    __shared__ int s_wave[16];
    __shared__ int s_total;
    __shared__ int s_cgt;
    __shared__ int s_ceq;
    __shared__ int s_keep;
    __shared__ int s_eq[64];

    uint32_t lo = 0;
    for (int bit = 30; bit >= 0; bit--) {
        uint32_t cand = lo | (1u << bit);
        int local = 0;
        #pragma unroll
        for (int i = 0; i < 32; i++) local += (u[i] >= cand) ? 1 : 0;
        #pragma unroll
        for (int off = 32; off > 0; off >>= 1) local += __shfl_down(local, off);
        if ((tid & 63) == 0) s_wave[tid >> 6] = local;
        __syncthreads();
        if (tid == 0) {
            int tot = 0;
            #pragma unroll
            for (int w = 0; w < 16; w++) tot += s_wave[w];
            s_total = tot;
        }
        __syncthreads();
        if (s_total >= TOPK) lo = cand;
        __syncthreads();
    }
    const uint32_t T = lo;

    if (tid == 0) { s_cgt = 0; s_ceq = 0; }
    __syncthreads();

    #pragma unroll
    for (int i = 0; i < 32; i++) {
        int idx = tid + (i << 10);
        if (u[i] > T) {
            int p = atomicAdd(&s_cgt, 1);
            wIdx[p * BATCH + row] = idx;
            wVal[p * BATCH + row] = __uint_as_float(u[i]);
        } else if (T != 0u && u[i] == T) {
            int p = atomicAdd(&s_ceq, 1);
            if (p < 64) s_eq[p] = idx;
        }
    }
    __syncthreads();

    if (tid == 0) {
        int c = s_cgt;
        int r = TOPK - c;
        if (T == 0u) {
            for (int q = 0; q < r; q++) {
                wIdx[(c + q) * BATCH + row] = 0;
                wVal[(c + q) * BATCH + row] = 0.0f;
            }
            s_keep = 0;
        } else {
            int e = s_ceq; if (e > 64) e = 64;
            for (int a2 = 1; a2 < e; a2++) {
                int key = s_eq[a2]; int b2 = a2 - 1;
                while (b2 >= 0 && s_eq[b2] > key) { s_eq[b2+1] = s_eq[b2]; b2--; }
                s_eq[b2+1] = key;
            }
            if (r > e) r = e;
            for (int q = 0; q < r; q++) {
                wIdx[(c + q) * BATCH + row] = s_eq[q];
                wVal[(c + q) * BATCH + row] = __uint_as_float(T);
            }
            for (int q = c + r; q < TOPK; q++) {
                wIdx[q * BATCH + row] = 0; wVal[q * BATCH + row] = 0.0f;
            }
            s_keep = r;
        }
    }
    __syncthreads();
    const int r2 = s_keep;

    #pragma unroll
    for (int i = 0; i < 32; i++) {
        int idx = tid + (i << 10);
        uint32_t uu = u[i];
        bool keep = uu > T;
        if (!keep && T != 0u && uu == T) {
            for (int q = 0; q < r2; q++) keep = keep || (s_eq[q] == idx);
        }
        hrow[idx] = keep ? __uint_as_float(uu) : 0.0f;
    }
}

// =====================================================================
extern "C" void kernel_launch(void* const* d_in, const int* in_sizes, int n_in,
                              void* d_out, int out_size, void* d_ws, size_t ws_size,
                              hipStream_t stream)
{
    const float* x  = (const float*)d_in[0];
    const float* We = (const float*)d_in[1];
    const float* be = (const float*)d_in[2];
    const float* Wd = (const float*)d_in[3];
    const float* bd = (const float*)d_in[4];

    float* xhat = (float*)d_out;                               // [2048,1024]
    float* h    = (float*)d_out + (size_t)BATCH * IN_DIM;      // [2048,32768]

    const size_t need = (size_t)BATCH * IN_DIM * 2      // x bf16
                      + (size_t)HID * IN_DIM * 2        // We bf16
                      + (size_t)TOPK * BATCH * 8;       // wIdx + wVal

    if (ws_size >= need) {
        ushort* xbf  = (ushort*)d_ws;
        ushort* wbf  = xbf + (size_t)BATCH * IN_DIM;
        int*    wIdx = (int*)(wbf + (size_t)HID * IN_DIM);
        float*  wVal = (float*)(wIdx + (size_t)TOPK * BATCH);

        to_bf16<<<(BATCH * IN_DIM / 4 + 255) / 256, 256, 0, stream>>>(x, xbf, BATCH * IN_DIM / 4);
        to_bf16<<<(HID * IN_DIM / 4 + 255) / 256, 256, 0, stream>>>(We, wbf, HID * IN_DIM / 4);
        encode_mfma<<<dim3(HID / 128, BATCH / 128), 256, 0, stream>>>(xbf, wbf, be, h);
        topk_rerank<<<BATCH, 1024, 0, stream>>>(h, x, We, be, wIdx, wVal);
        decode_sparse<<<IN_DIM, 256, 65536, stream>>>(Wd, bd, wIdx, wVal, xhat);
    } else {
        int*   wIdx = (int*)d_ws;
        float* wVal = (float*)((char*)d_ws + sizeof(int) * BATCH * TOPK);
        dim3 g1(HID / BN, BATCH / BM);
        encode_gemm<<<g1, 256, 0, stream>>>(x, We, be, h);
        topk_mask<<<BATCH, 1024, 0, stream>>>(h, wIdx, wVal);
        decode_sparse<<<IN_DIM, 256, 65536, stream>>>(Wd, bd, wIdx, wVal, xhat);
    }
}

// Round 3
// 930.323 us; speedup vs baseline: 3.4321x; 1.5445x over previous
//
#include <hip/hip_runtime.h>
#include <stdint.h>

#define BATCH 2048
#define IN_DIM 1024
#define HID 32768
#define TOPK 32

typedef __attribute__((ext_vector_type(8))) short short8;
typedef __attribute__((ext_vector_type(4))) float f32x4;

// =====================================================================
// FAST PATH
// =====================================================================

// ---------- fp32 -> bf16 (RNE), n4 = element count / 4 ----------
__global__ __launch_bounds__(256) void to_bf16(const float* __restrict__ src,
                                               ushort* __restrict__ dst, int n4)
{
    int i = blockIdx.x * 256 + threadIdx.x;
    if (i >= n4) return;
    float4 v = ((const float4*)src)[i];
    ushort4 o;
    uint32_t u;
    u = __float_as_uint(v.x); o.x = (ushort)((u + 0x7FFFu + ((u >> 16) & 1u)) >> 16);
    u = __float_as_uint(v.y); o.y = (ushort)((u + 0x7FFFu + ((u >> 16) & 1u)) >> 16);
    u = __float_as_uint(v.z); o.z = (ushort)((u + 0x7FFFu + ((u >> 16) & 1u)) >> 16);
    u = __float_as_uint(v.w); o.w = (ushort)((u + 0x7FFFu + ((u >> 16) & 1u)) >> 16);
    ((ushort4*)dst)[i] = o;
}

// ---------- bf16 MFMA encode: approx = relu(x @ We^T + be) ----------
__global__ __launch_bounds__(256) void encode_mfma(
    const ushort* __restrict__ xb, const ushort* __restrict__ wb,
    const float* __restrict__ be, float* __restrict__ out)
{
    __shared__ __align__(16) ushort As[128 * 32];   // [row][k], 64B rows, no pad
    __shared__ __align__(16) ushort Bs[128 * 32];
    const int t    = threadIdx.x;
    const int wave = t >> 6;
    const int lane = t & 63;
    const int m0 = blockIdx.y * 128;
    const int n0 = blockIdx.x * 128;
    const int wm = (wave >> 1) * 64;
    const int wn = (wave & 1) * 64;

    const int srow = lane >> 2;
    const int scol = (lane & 3) * 8;
    const ushort* gA0 = xb + (size_t)(m0 + wave * 32 + srow) * IN_DIM + scol;
    const ushort* gA1 = gA0 + 16 * IN_DIM;
    const ushort* gB0 = wb + (size_t)(n0 + wave * 32 + srow) * IN_DIM + scol;
    const ushort* gB1 = gB0 + 16 * IN_DIM;
    ushort* lA0 = &As[(wave * 32 + 0)  * 32];
    ushort* lA1 = &As[(wave * 32 + 16) * 32];
    ushort* lB0 = &Bs[(wave * 32 + 0)  * 32];
    ushort* lB1 = &Bs[(wave * 32 + 16) * 32];

    f32x4 acc[4][4];
    #pragma unroll
    for (int i = 0; i < 4; i++)
        #pragma unroll
        for (int j = 0; j < 4; j++) acc[i][j] = 0.f;

    const int fr   = lane & 15;
    const int quad = lane >> 4;

    for (int kt = 0; kt < IN_DIM; kt += 32) {
        __builtin_amdgcn_global_load_lds((const __attribute__((address_space(1))) void*)(gA0 + kt),
                                         (__attribute__((address_space(3))) void*)lA0, 16, 0, 0);
        __builtin_amdgcn_global_load_lds((const __attribute__((address_space(1))) void*)(gA1 + kt),
                                         (__attribute__((address_space(3))) void*)lA1, 16, 0, 0);
        __builtin_amdgcn_global_load_lds((const __attribute__((address_space(1))) void*)(gB0 + kt),
                                         (__attribute__((address_space(3))) void*)lB0, 16, 0, 0);
        __builtin_amdgcn_global_load_lds((const __attribute__((address_space(1))) void*)(gB1 + kt),
                                         (__attribute__((address_space(3))) void*)lB1, 16, 0, 0);
        __syncthreads();
        short8 af[4], bf[4];
        #pragma unroll
        for (int i = 0; i < 4; i++) {
            af[i] = *(const short8*)&As[(wm + i * 16 + fr) * 32 + quad * 8];
            bf[i] = *(const short8*)&Bs[(wn + i * 16 + fr) * 32 + quad * 8];
        }
        #pragma unroll
        for (int mt = 0; mt < 4; mt++)
            #pragma unroll
            for (int nt = 0; nt < 4; nt++)
                acc[mt][nt] = __builtin_amdgcn_mfma_f32_16x16x32_bf16(
                    af[mt], bf[nt], acc[mt][nt], 0, 0, 0);
        __syncthreads();
    }

    #pragma unroll
    for (int nt = 0; nt < 4; nt++) {
        const int n = n0 + wn + nt * 16 + fr;
        const float bias = be[n];
        #pragma unroll
        for (int mt = 0; mt < 4; mt++) {
            #pragma unroll
            for (int r = 0; r < 4; r++) {
                const int m = m0 + wm + mt * 16 + quad * 4 + r;
                float v = acc[mt][nt][r] + bias;
                out[(size_t)m * HID + n] = v > 0.f ? v : 0.f;
            }
        }
    }
}

// ---------- topk + exact fp32 re-rank + final h write ----------
#define DELTA 0.0625f
#define MAXC 512

__global__ __launch_bounds__(1024) void topk_rerank(
    float* __restrict__ hbuf,
    const float* __restrict__ x, const float* __restrict__ We,
    const float* __restrict__ be,
    int* __restrict__ wIdx, float* __restrict__ wVal)
{
    const int row = blockIdx.x;
    const int tid = threadIdx.x;
    float* hrow = hbuf + (size_t)row * HID;

    float a[32];
    #pragma unroll
    for (int i = 0; i < 32; i++) a[i] = hrow[tid + (i << 10)];

    __shared__ int   hist[256];
    __shared__ float s_thresh;
    __shared__ int   c_n;
    __shared__ int   c_idx[MAXC];
    __shared__ float c_val[MAXC];
    __shared__ float xs[IN_DIM];
    __shared__ int   win_i[TOPK];
    __shared__ float win_v[TOPK];

    if (tid < 256) hist[tid] = 0;
    xs[tid] = x[(size_t)row * IN_DIM + tid];
    if (tid == 0) c_n = 0;
    __syncthreads();

    #pragma unroll
    for (int i = 0; i < 32; i++) {
        if (a[i] > 0.f) {
            int b = (int)(a[i] * 128.f); if (b > 255) b = 255;
            atomicAdd(&hist[b], 1);
        }
    }
    __syncthreads();

    if (tid == 0) {
        int acc = 0, b = 255;
        for (; b >= 0; b--) { acc += hist[b]; if (acc >= TOPK) break; }
        s_thresh = (b >= 0) ? ((float)b * (1.f / 128.f) - DELTA) : 0.f;
    }
    __syncthreads();
    const float th = s_thresh;

    #pragma unroll
    for (int i = 0; i < 32; i++) {
        if (a[i] > 0.f && a[i] >= th) {
            int p = atomicAdd(&c_n, 1);
            if (p < MAXC) c_idx[p] = tid + (i << 10);
        }
    }
    __syncthreads();
    const int nc = c_n < MAXC ? c_n : MAXC;

    const int wv = tid >> 6, ln = tid & 63;
    for (int c = wv; c < nc; c += 16) {
        const float4* wr = (const float4*)(We + (size_t)c_idx[c] * IN_DIM);
        const float4* xv = (const float4*)xs;
        float s = 0.f;
        #pragma unroll
        for (int q = 0; q < 4; q++) {
            float4 w4 = wr[ln * 4 + q];
            float4 x4 = xv[ln * 4 + q];
            s += w4.x * x4.x + w4.y * x4.y + w4.z * x4.z + w4.w * x4.w;
        }
        #pragma unroll
        for (int off = 32; off > 0; off >>= 1) s += __shfl_down(s, off);
        if (ln == 0) {
            s += be[c_idx[c]];
            c_val[c] = s > 0.f ? s : 0.f;
        }
    }
    if (tid < TOPK) {
        win_i[tid] = -1; win_v[tid] = 0.f;
        wIdx[tid * BATCH + row] = 0;
        wVal[tid * BATCH + row] = 0.f;
    }
    __syncthreads();

    if (tid < nc) {
        const float v = c_val[tid];
        const int  id = c_idx[tid];
        int r = 0;
        for (int j = 0; j < nc; j++) {
            float vj = c_val[j]; int ij = c_idx[j];
            r += (vj > v) || (vj == v && ij < id) ? 1 : 0;
        }
        if (r < TOPK) {
            win_i[r] = id; win_v[r] = v;
            wIdx[r * BATCH + row] = id;
            wVal[r * BATCH + row] = v;
        }
    }
    __syncthreads();

    float4* h4 = (float4*)hrow;
    float4 z; z.x = z.y = z.z = z.w = 0.f;
    #pragma unroll
    for (int i = 0; i < 8; i++) h4[tid + (i << 10)] = z;
    __syncthreads();
    if (tid < TOPK && win_i[tid] >= 0)
        hrow[win_i[tid]] = win_v[tid];
}

// ---------- Wd transpose: WdT[j][i] = Wd[i][j] ----------
// 64x64 tiles, LDS pad 65 (2-way alias only = free). grid (HID/64, IN_DIM/64).
__global__ __launch_bounds__(256) void transpose_wd(
    const float* __restrict__ Wd, float* __restrict__ WdT)
{
    __shared__ float tile[64][65];
    const int t  = threadIdx.x;
    const int j0 = blockIdx.x * 64;   // HID
    const int i0 = blockIdx.y * 64;   // IN_DIM
    const int c4 = (t & 15) * 4;
    const int r0 = t >> 4;            // 0..15

    #pragma unroll
    for (int s = 0; s < 4; s++) {
        const int r = r0 + s * 16;
        float4 v = *(const float4*)&Wd[(size_t)(i0 + r) * HID + j0 + c4];
        tile[r][c4 + 0] = v.x; tile[r][c4 + 1] = v.y;
        tile[r][c4 + 2] = v.z; tile[r][c4 + 3] = v.w;
    }
    __syncthreads();
    #pragma unroll
    for (int s = 0; s < 4; s++) {
        const int jr = r0 + s * 16;
        float4 o;
        o.x = tile[c4 + 0][jr]; o.y = tile[c4 + 1][jr];
        o.z = tile[c4 + 2][jr]; o.w = tile[c4 + 3][jr];
        *(float4*)&WdT[(size_t)(j0 + jr) * IN_DIM + i0 + c4] = o;
    }
}

// ---------- batch-major sparse decode from WdT ----------
// one block per batch row; thread t owns x_hat[b, 4t..4t+3].
__global__ __launch_bounds__(256) void decode_gather(
    const float* __restrict__ WdT, const float* __restrict__ bd,
    const int* __restrict__ wIdx, const float* __restrict__ wVal,
    float* __restrict__ xhat)
{
    const int b = blockIdx.x;
    const int t = threadIdx.x;
    __shared__ int   s_idx[TOPK];
    __shared__ float s_val[TOPK];
    if (t < TOPK) {
        s_idx[t] = wIdx[t * BATCH + b];
        s_val[t] = wVal[t * BATCH + b];
    }
    float4 acc = ((const float4*)bd)[t];
    __syncthreads();
    #pragma unroll 8
    for (int k = 0; k < TOPK; k++) {
        const float4 w = ((const float4*)(WdT + (size_t)s_idx[k] * IN_DIM))[t];
        const float  v = s_val[k];
        acc.x += v * w.x; acc.y += v * w.y; acc.z += v * w.z; acc.w += v * w.w;
    }
    ((float4*)(xhat + (size_t)b * IN_DIM))[t] = acc;
}

// ---------- old LDS-chunk decode (fallback when ws can't hold WdT) ----------
#define DCHUNK 16384

__global__ __launch_bounds__(256) void decode_sparse(
    const float* __restrict__ Wd, const float* __restrict__ bd,
    const int* __restrict__ wIdx, const float* __restrict__ wVal,
    float* __restrict__ xhat)
{
    extern __shared__ float lds[];
    const int i = blockIdx.x;
    const int t = threadIdx.x;
    const float* wrow = Wd + (size_t)i * HID;
    const float bias = bd[i];
    float acc[8];
    #pragma unroll
    for (int q = 0; q < 8; q++) acc[q] = bias;

    for (int ch = 0; ch < HID / DCHUNK; ch++) {
        __syncthreads();
        const float4* src = (const float4*)(wrow + ch * DCHUNK);
        #pragma unroll
        for (int j = 0; j < DCHUNK / 4 / 256; j++)
            ((float4*)lds)[t + j * 256] = src[t + j * 256];
        __syncthreads();
        const uint32_t base = (uint32_t)(ch * DCHUNK);
        #pragma unroll
        for (int q = 0; q < 8; q++) {
            const int b = t + (q << 8);
            #pragma unroll 4
            for (int k = 0; k < TOPK; k++) {
                uint32_t off = (uint32_t)wIdx[(k << 11) + b] - base;
                if (off < (uint32_t)DCHUNK)
                    acc[q] += wVal[(k << 11) + b] * lds[off];
            }
        }
    }
    #pragma unroll
    for (int q = 0; q < 8; q++) {
        const int b = t + (q << 8);
        xhat[(size_t)b * IN_DIM + i] = acc[q];
    }
}

// =====================================================================
// FALLBACK PATH (round-1 fp32) — used only if ws_size is tiny
// =====================================================================
#define BM 64
#define BN 128
#define BK 16
#define LDA 68
#define LDB 132

__global__ __launch_bounds__(256) void encode_gemm(
    const float* __restrict__ x, const float* __restrict__ We,
    const float* __restrict__ be, float* __restrict__ h)
{
    __shared__ __align__(16) float As[BK][LDA];
    __shared__ __align__(16) float Bs[BK][LDB];
    const int n0 = blockIdx.x * BN;
    const int m0 = blockIdx.y * BM;
    const int t  = threadIdx.x;
    const int tx = t & 15;
    const int ty = t >> 4;
    const int ar = t >> 2;
    const int ak = (t & 3) * 4;

    const float* ap  = x  + (size_t)(m0 + ar) * IN_DIM + ak;
    const float* bp0 = We + (size_t)(n0 + ar) * IN_DIM + ak;
    const float* bp1 = We + (size_t)(n0 + 64 + ar) * IN_DIM + ak;

    float acc[4][8] = {};
    for (int kt = 0; kt < IN_DIM; kt += BK) {
        float4 av  = *(const float4*)(ap  + kt);
        float4 bv0 = *(const float4*)(bp0 + kt);
        float4 bv1 = *(const float4*)(bp1 + kt);
        __syncthreads();
        As[ak+0][ar] = av.x;  As[ak+1][ar] = av.y;  As[ak+2][ar] = av.z;  As[ak+3][ar] = av.w;
        Bs[ak+0][ar] = bv0.x; Bs[ak+1][ar] = bv0.y; Bs[ak+2][ar] = bv0.z; Bs[ak+3][ar] = bv0.w;
        Bs[ak+0][ar+64] = bv1.x; Bs[ak+1][ar+64] = bv1.y; Bs[ak+2][ar+64] = bv1.z; Bs[ak+3][ar+64] = bv1.w;
        __syncthreads();
        #pragma unroll
        for (int kk = 0; kk < BK; kk++) {
            float a_[4], b_[8];
            *(float4*)a_     = *(const float4*)&As[kk][ty*4];
            *(float4*)b_     = *(const float4*)&Bs[kk][tx*8];
            *(float4*)(b_+4) = *(const float4*)&Bs[kk][tx*8+4];
            #pragma unroll
            for (int i = 0; i < 4; i++)
                #pragma unroll
                for (int j = 0; j < 8; j++)
                    acc[i][j] += a_[i] * b_[j];
        }
    }
    float be_[8];
    *(float4*)be_     = *(const float4*)&be[n0 + tx*8];
    *(float4*)(be_+4) = *(const float4*)&be[n0 + tx*8 + 4];
    #pragma unroll
    for (int i = 0; i < 4; i++) {
        float o[8];
        #pragma unroll
        for (int j = 0; j < 8; j++) {
            float v = acc[i][j] + be_[j];
            o[j] = v > 0.0f ? v : 0.0f;
        }
        float* dst = h + (size_t)(m0 + ty*4 + i) * HID + n0 + tx*8;
        *(float4*)dst     = *(const float4*)o;
        *(float4*)(dst+4) = *(const float4*)(o+4);
    }
}

__global__ __launch_bounds__(1024) void topk_mask(
    float* __restrict__ h, int* __restrict__ wIdx, float* __restrict__ wVal)
{
    const int row = blockIdx.x;
    const int tid = threadIdx.x;
    float* hrow = h + (size_t)row * HID;

    uint32_t u[32];
    #pragma unroll
    for (int i = 0; i < 32; i++)
        u[i] = __float_as_uint(hrow[tid + (i << 10)]);

    __shared__ int s_wave[16];
    __shared__ int s_total;
    __shared__ int s_cgt;
    __shared__ int s_ceq;
    __shared__ int s_keep;
    __shared__ int s_eq[64];

    uint32_t lo = 0;
    for (int bit = 30; bit >= 0; bit--) {
        uint32_t cand = lo | (1u << bit);
        int local = 0;
        #pragma unroll
        for (int i = 0; i < 32; i++) local += (u[i] >= cand) ? 1 : 0;
        #pragma unroll
        for (int off = 32; off > 0; off >>= 1) local += __shfl_down(local, off);
        if ((tid & 63) == 0) s_wave[tid >> 6] = local;
        __syncthreads();
        if (tid == 0) {
            int tot = 0;
            #pragma unroll
            for (int w = 0; w < 16; w++) tot += s_wave[w];
            s_total = tot;
        }
        __syncthreads();
        if (s_total >= TOPK) lo = cand;
        __syncthreads();
    }
    const uint32_t T = lo;

    if (tid == 0) { s_cgt = 0; s_ceq = 0; }
    __syncthreads();

    #pragma unroll
    for (int i = 0; i < 32; i++) {
        int idx = tid + (i << 10);
        if (u[i] > T) {
            int p = atomicAdd(&s_cgt, 1);
            wIdx[p * BATCH + row] = idx;
            wVal[p * BATCH + row] = __uint_as_float(u[i]);
        } else if (T != 0u && u[i] == T) {
            int p = atomicAdd(&s_ceq, 1);
            if (p < 64) s_eq[p] = idx;
        }
    }
    __syncthreads();

    if (tid == 0) {
        int c = s_cgt;
        int r = TOPK - c;
        if (T == 0u) {
            for (int q = 0; q < r; q++) {
                wIdx[(c + q) * BATCH + row] = 0;
                wVal[(c + q) * BATCH + row] = 0.0f;
            }
            s_keep = 0;
        } else {
            int e = s_ceq; if (e > 64) e = 64;
            for (int a2 = 1; a2 < e; a2++) {
                int key = s_eq[a2]; int b2 = a2 - 1;
                while (b2 >= 0 && s_eq[b2] > key) { s_eq[b2+1] = s_eq[b2]; b2--; }
                s_eq[b2+1] = key;
            }
            if (r > e) r = e;
            for (int q = 0; q < r; q++) {
                wIdx[(c + q) * BATCH + row] = s_eq[q];
                wVal[(c + q) * BATCH + row] = __uint_as_float(T);
            }
            for (int q = c + r; q < TOPK; q++) {
                wIdx[q * BATCH + row] = 0; wVal[q * BATCH + row] = 0.0f;
            }
            s_keep = r;
        }
    }
    __syncthreads();
    const int r2 = s_keep;

    #pragma unroll
    for (int i = 0; i < 32; i++) {
        int idx = tid + (i << 10);
        uint32_t uu = u[i];
        bool keep = uu > T;
        if (!keep && T != 0u && uu == T) {
            for (int q = 0; q < r2; q++) keep = keep || (s_eq[q] == idx);
        }
        hrow[idx] = keep ? __uint_as_float(uu) : 0.0f;
    }
}

// =====================================================================
extern "C" void kernel_launch(void* const* d_in, const int* in_sizes, int n_in,
                              void* d_out, int out_size, void* d_ws, size_t ws_size,
                              hipStream_t stream)
{
    const float* x  = (const float*)d_in[0];
    const float* We = (const float*)d_in[1];
    const float* be = (const float*)d_in[2];
    const float* Wd = (const float*)d_in[3];
    const float* bd = (const float*)d_in[4];

    float* xhat = (float*)d_out;                               // [2048,1024]
    float* h    = (float*)d_out + (size_t)BATCH * IN_DIM;      // [2048,32768]

    const size_t MiB = 1ull << 20;
    // ws layout (fast path): xbf @0 (4 MiB), wbf @4 (64 MiB),
    // wIdx @68 (256 KiB), wVal @68.25 (256 KiB), WdT @69 (128 MiB)
    const size_t need_mid  = 69 * MiB;
    const size_t need_full = 69 * MiB + (size_t)HID * IN_DIM * 4;   // +128 MiB

    if (ws_size >= need_mid) {
        ushort* xbf  = (ushort*)d_ws;
        ushort* wbf  = (ushort*)((char*)d_ws + 4 * MiB);
        int*    wIdx = (int*)   ((char*)d_ws + 68 * MiB);
        float*  wVal = (float*) ((char*)d_ws + 68 * MiB + 256 * 1024);
        float*  WdT  = (float*) ((char*)d_ws + 69 * MiB);

        to_bf16<<<(BATCH * IN_DIM / 4 + 255) / 256, 256, 0, stream>>>(x, xbf, BATCH * IN_DIM / 4);
        to_bf16<<<(HID * IN_DIM / 4 + 255) / 256, 256, 0, stream>>>(We, wbf, HID * IN_DIM / 4);
        encode_mfma<<<dim3(HID / 128, BATCH / 128), 256, 0, stream>>>(xbf, wbf, be, h);
        topk_rerank<<<BATCH, 1024, 0, stream>>>(h, x, We, be, wIdx, wVal);
        if (ws_size >= need_full) {
            transpose_wd<<<dim3(HID / 64, IN_DIM / 64), 256, 0, stream>>>(Wd, WdT);
            decode_gather<<<BATCH, 256, 0, stream>>>(WdT, bd, wIdx, wVal, xhat);
        } else {
            decode_sparse<<<IN_DIM, 256, 65536, stream>>>(Wd, bd, wIdx, wVal, xhat);
        }
    } else {
        int*   wIdx = (int*)d_ws;
        float* wVal = (float*)((char*)d_ws + sizeof(int) * BATCH * TOPK);
        dim3 g1(HID / BN, BATCH / BM);
        encode_gemm<<<g1, 256, 0, stream>>>(x, We, be, h);
        topk_mask<<<BATCH, 1024, 0, stream>>>(h, wIdx, wVal);
        decode_sparse<<<IN_DIM, 256, 65536, stream>>>(Wd, bd, wIdx, wVal, xhat);
    }
}

// Round 4
// 855.257 us; speedup vs baseline: 3.7333x; 1.0878x over previous
//
#include <hip/hip_runtime.h>
#include <stdint.h>

#define BATCH 2048
#define IN_DIM 1024
#define HID 32768
#define TOPK 32

typedef __attribute__((ext_vector_type(8))) short short8;
typedef __attribute__((ext_vector_type(8))) unsigned short ushort8v;
typedef __attribute__((ext_vector_type(4))) float f32x4;

__device__ __forceinline__ ushort f2bf(float f) {
    uint32_t u = __float_as_uint(f);
    return (ushort)((u + 0x7FFFu + ((u >> 16) & 1u)) >> 16);
}

// =====================================================================
// FAST PATH
// =====================================================================

// ---------- fp32 -> bf16 (RNE), n4 = element count / 4 ----------
__global__ __launch_bounds__(256) void to_bf16(const float* __restrict__ src,
                                               ushort* __restrict__ dst, int n4)
{
    int i = blockIdx.x * 256 + threadIdx.x;
    if (i >= n4) return;
    float4 v = ((const float4*)src)[i];
    ushort4 o;
    o.x = f2bf(v.x); o.y = f2bf(v.y); o.z = f2bf(v.z); o.w = f2bf(v.w);
    ((ushort4*)dst)[i] = o;
}

// ---------- bf16 MFMA encode ----------
// Writes: happ = bf16(relu(x@We^T + be))  [BATCH][HID]  (LDS-repacked, ushort8)
//         h    = zeros (final h is zeros + scattered winners from topk_rerank)
#define SH_LD 136   // ushort row stride for repack tile; 272B rows (16B-aligned)

__global__ __launch_bounds__(256) void encode_mfma(
    const ushort* __restrict__ xb, const ushort* __restrict__ wb,
    const float* __restrict__ be, ushort* __restrict__ happ,
    float* __restrict__ h)
{
    __shared__ __align__(16) ushort As[128 * 32];   // [row][k], 64B rows
    __shared__ __align__(16) ushort Bs[128 * 32];
    __shared__ __align__(16) ushort s_h[128 * SH_LD];
    const int t    = threadIdx.x;
    const int wave = t >> 6;
    const int lane = t & 63;
    const int m0 = blockIdx.y * 128;
    const int n0 = blockIdx.x * 128;
    const int wm = (wave >> 1) * 64;
    const int wn = (wave & 1) * 64;

    const int srow = lane >> 2;
    const int scol = (lane & 3) * 8;
    const ushort* gA0 = xb + (size_t)(m0 + wave * 32 + srow) * IN_DIM + scol;
    const ushort* gA1 = gA0 + 16 * IN_DIM;
    const ushort* gB0 = wb + (size_t)(n0 + wave * 32 + srow) * IN_DIM + scol;
    const ushort* gB1 = gB0 + 16 * IN_DIM;
    ushort* lA0 = &As[(wave * 32 + 0)  * 32];
    ushort* lA1 = &As[(wave * 32 + 16) * 32];
    ushort* lB0 = &Bs[(wave * 32 + 0)  * 32];
    ushort* lB1 = &Bs[(wave * 32 + 16) * 32];

    f32x4 acc[4][4];
    #pragma unroll
    for (int i = 0; i < 4; i++)
        #pragma unroll
        for (int j = 0; j < 4; j++) acc[i][j] = 0.f;

    const int fr   = lane & 15;
    const int quad = lane >> 4;

    for (int kt = 0; kt < IN_DIM; kt += 32) {
        __builtin_amdgcn_global_load_lds((const __attribute__((address_space(1))) void*)(gA0 + kt),
                                         (__attribute__((address_space(3))) void*)lA0, 16, 0, 0);
        __builtin_amdgcn_global_load_lds((const __attribute__((address_space(1))) void*)(gA1 + kt),
                                         (__attribute__((address_space(3))) void*)lA1, 16, 0, 0);
        __builtin_amdgcn_global_load_lds((const __attribute__((address_space(1))) void*)(gB0 + kt),
                                         (__attribute__((address_space(3))) void*)lB0, 16, 0, 0);
        __builtin_amdgcn_global_load_lds((const __attribute__((address_space(1))) void*)(gB1 + kt),
                                         (__attribute__((address_space(3))) void*)lB1, 16, 0, 0);
        __syncthreads();
        short8 af[4], bf[4];
        #pragma unroll
        for (int i = 0; i < 4; i++) {
            af[i] = *(const short8*)&As[(wm + i * 16 + fr) * 32 + quad * 8];
            bf[i] = *(const short8*)&Bs[(wn + i * 16 + fr) * 32 + quad * 8];
        }
        #pragma unroll
        for (int mt = 0; mt < 4; mt++)
            #pragma unroll
            for (int nt = 0; nt < 4; nt++)
                acc[mt][nt] = __builtin_amdgcn_mfma_f32_16x16x32_bf16(
                    af[mt], bf[nt], acc[mt][nt], 0, 0, 0);
        __syncthreads();
    }

    // --- zero the h tile (independent global stores, issue early) ---
    {
        float4 z; z.x = z.y = z.z = z.w = 0.f;
        #pragma unroll
        for (int j = 0; j < 16; j++) {
            const int idx = t + j * 256;       // 4096 float4 slots = 128x128
            const int r = idx >> 5, c = idx & 31;
            ((float4*)(h + (size_t)(m0 + r) * HID + n0))[c] = z;
        }
    }

    // --- bias+relu, bf16, repack via LDS ---
    // C/D layout: col(n)=lane&15, row(m)=quad*4+reg  [m89/m91-verified]
    #pragma unroll
    for (int nt = 0; nt < 4; nt++) {
        const int nl = wn + nt * 16 + fr;
        const float bias = be[n0 + nl];
        #pragma unroll
        for (int mt = 0; mt < 4; mt++) {
            #pragma unroll
            for (int r = 0; r < 4; r++) {
                const int ml = wm + mt * 16 + quad * 4 + r;
                float v = acc[mt][nt][r] + bias;
                s_h[ml * SH_LD + nl] = f2bf(v > 0.f ? v : 0.f);
            }
        }
    }
    __syncthreads();
    #pragma unroll
    for (int j = 0; j < 8; j++) {
        const int idx = t + j * 256;           // 2048 ushort8 slots = 128x128
        const int r = idx >> 4, c = idx & 15;
        ((ushort8v*)(happ + (size_t)(m0 + r) * HID + n0))[c] =
            *(const ushort8v*)(s_h + r * SH_LD + c * 8);
    }
}

// ---------- topk + exact fp32 re-rank + winner scatter ----------
// happ: bf16 approx scores. h: pre-zeroed by encode; only winners written.
#define DELTA 0.09375f
#define MAXC 512

__global__ __launch_bounds__(1024) void topk_rerank(
    const ushort* __restrict__ happ, float* __restrict__ h,
    const float* __restrict__ x, const float* __restrict__ We,
    const float* __restrict__ be,
    int* __restrict__ wIdx, float* __restrict__ wVal)
{
    const int row = blockIdx.x;
    const int tid = threadIdx.x;

    // per-thread contiguous 32 scores: fully vectorized 4x ushort8 loads
    float a[32];
    {
        const ushort8v* hp = (const ushort8v*)(happ + (size_t)row * HID + tid * 32);
        #pragma unroll
        for (int j = 0; j < 4; j++) {
            ushort8v u8 = hp[j];
            #pragma unroll
            for (int e = 0; e < 8; e++)
                a[j * 8 + e] = __uint_as_float(((uint32_t)u8[e]) << 16);
        }
    }

    __shared__ int   hist[256];
    __shared__ int   s_wave[16];
    __shared__ int   s_c05;
    __shared__ float s_thresh;
    __shared__ int   c_n;
    __shared__ int   c_idx[MAXC];
    __shared__ float c_val[MAXC];
    __shared__ float xs[IN_DIM];
    __shared__ int   win_i[TOPK];
    __shared__ float win_v[TOPK];

    if (tid < 256) hist[tid] = 0;
    xs[tid] = x[(size_t)row * IN_DIM + tid];
    if (tid == 0) c_n = 0;

    // count values >= 0.5 (no atomics)
    int loc = 0;
    #pragma unroll
    for (int i = 0; i < 32; i++) loc += (a[i] >= 0.5f) ? 1 : 0;
    #pragma unroll
    for (int off = 32; off > 0; off >>= 1) loc += __shfl_down(loc, off);
    if ((tid & 63) == 0) s_wave[tid >> 6] = loc;
    __syncthreads();
    if (tid == 0) {
        int tot = 0;
        #pragma unroll
        for (int w = 0; w < 16; w++) tot += s_wave[w];
        s_c05 = tot;
    }
    __syncthreads();

    const bool  hi   = (s_c05 >= TOPK);   // top-32 all >= 0.5 in this case
    const float base = hi ? 0.5f : 0.0f;

    // histogram only the relevant tail (~1900 values/row in hi case)
    #pragma unroll
    for (int i = 0; i < 32; i++) {
        const bool in = hi ? (a[i] >= 0.5f) : (a[i] > 0.f);
        if (in) {
            int b = (int)((a[i] - base) * 128.f);
            if (b > 255) b = 255;
            atomicAdd(&hist[b], 1);
        }
    }
    __syncthreads();

    if (tid == 0) {
        int acc = 0, b = 255;
        for (; b >= 0; b--) { acc += hist[b]; if (acc >= TOPK) break; }
        s_thresh = (b >= 0) ? (base + (float)b * (1.f / 128.f) - DELTA) : 0.f;
    }
    __syncthreads();
    const float th = s_thresh;

    #pragma unroll
    for (int i = 0; i < 32; i++) {
        if (a[i] > 0.f && a[i] >= th) {
            int p = atomicAdd(&c_n, 1);
            if (p < MAXC) c_idx[p] = tid * 32 + i;
        }
    }
    __syncthreads();
    const int nc = c_n < MAXC ? c_n : MAXC;

    // exact fp32 recompute, one wave per candidate
    const int wv = tid >> 6, ln = tid & 63;
    for (int c = wv; c < nc; c += 16) {
        const float4* wr = (const float4*)(We + (size_t)c_idx[c] * IN_DIM);
        const float4* xv = (const float4*)xs;
        float s = 0.f;
        #pragma unroll
        for (int q = 0; q < 4; q++) {
            float4 w4 = wr[ln * 4 + q];
            float4 x4 = xv[ln * 4 + q];
            s += w4.x * x4.x + w4.y * x4.y + w4.z * x4.z + w4.w * x4.w;
        }
        #pragma unroll
        for (int off = 32; off > 0; off >>= 1) s += __shfl_down(s, off);
        if (ln == 0) {
            s += be[c_idx[c]];
            c_val[c] = s > 0.f ? s : 0.f;
        }
    }
    if (tid < TOPK) {   // prefill (covers nc < 32)
        win_i[tid] = -1; win_v[tid] = 0.f;
        wIdx[tid * BATCH + row] = 0;
        wVal[tid * BATCH + row] = 0.f;
    }
    __syncthreads();

    // exact ranking, ties -> lowest index (jax.lax.top_k semantics)
    if (tid < nc) {
        const float v = c_val[tid];
        const int  id = c_idx[tid];
        int r = 0;
        for (int j = 0; j < nc; j++) {
            float vj = c_val[j]; int ij = c_idx[j];
            r += (vj > v) || (vj == v && ij < id) ? 1 : 0;
        }
        if (r < TOPK) {
            win_i[r] = id; win_v[r] = v;
            wIdx[r * BATCH + row] = id;
            wVal[r * BATCH + row] = v;
        }
    }
    __syncthreads();

    // h is pre-zeroed by encode; scatter the exact winners only
    if (tid < TOPK && win_i[tid] >= 0)
        h[(size_t)row * HID + win_i[tid]] = win_v[tid];
}

// ---------- Wd transpose: WdT[j][i] = Wd[i][j] ----------
__global__ __launch_bounds__(256) void transpose_wd(
    const float* __restrict__ Wd, float* __restrict__ WdT)
{
    __shared__ float tile[64][65];
    const int t  = threadIdx.x;
    const int j0 = blockIdx.x * 64;   // HID
    const int i0 = blockIdx.y * 64;   // IN_DIM
    const int c4 = (t & 15) * 4;
    const int r0 = t >> 4;

    #pragma unroll
    for (int s = 0; s < 4; s++) {
        const int r = r0 + s * 16;
        float4 v = *(const float4*)&Wd[(size_t)(i0 + r) * HID + j0 + c4];
        tile[r][c4 + 0] = v.x; tile[r][c4 + 1] = v.y;
        tile[r][c4 + 2] = v.z; tile[r][c4 + 3] = v.w;
    }
    __syncthreads();
    #pragma unroll
    for (int s = 0; s < 4; s++) {
        const int jr = r0 + s * 16;
        float4 o;
        o.x = tile[c4 + 0][jr]; o.y = tile[c4 + 1][jr];
        o.z = tile[c4 + 2][jr]; o.w = tile[c4 + 3][jr];
        *(float4*)&WdT[(size_t)(j0 + jr) * IN_DIM + i0 + c4] = o;
    }
}

// ---------- batch-major sparse decode from WdT ----------
__global__ __launch_bounds__(256) void decode_gather(
    const float* __restrict__ WdT, const float* __restrict__ bd,
    const int* __restrict__ wIdx, const float* __restrict__ wVal,
    float* __restrict__ xhat)
{
    const int b = blockIdx.x;
    const int t = threadIdx.x;
    __shared__ int   s_idx[TOPK];
    __shared__ float s_val[TOPK];
    if (t < TOPK) {
        s_idx[t] = wIdx[t * BATCH + b];
        s_val[t] = wVal[t * BATCH + b];
    }
    float4 acc = ((const float4*)bd)[t];
    __syncthreads();
    #pragma unroll 8
    for (int k = 0; k < TOPK; k++) {
        const float4 w = ((const float4*)(WdT + (size_t)s_idx[k] * IN_DIM))[t];
        const float  v = s_val[k];
        acc.x += v * w.x; acc.y += v * w.y; acc.z += v * w.z; acc.w += v * w.w;
    }
    ((float4*)(xhat + (size_t)b * IN_DIM))[t] = acc;
}

// =====================================================================
// FALLBACK PATH (fp32, round-1; used only if ws_size < 197 MiB)
// =====================================================================
#define BM 64
#define BN 128
#define BK 16
#define LDA 68
#define LDB 132

__global__ __launch_bounds__(256) void encode_gemm(
    const float* __restrict__ x, const float* __restrict__ We,
    const float* __restrict__ be, float* __restrict__ h)
{
    __shared__ __align__(16) float As2[BK][LDA];
    __shared__ __align__(16) float Bs2[BK][LDB];
    const int n0 = blockIdx.x * BN;
    const int m0 = blockIdx.y * BM;
    const int t  = threadIdx.x;
    const int tx = t & 15;
    const int ty = t >> 4;
    const int ar = t >> 2;
    const int ak = (t & 3) * 4;

    const float* ap  = x  + (size_t)(m0 + ar) * IN_DIM + ak;
    const float* bp0 = We + (size_t)(n0 + ar) * IN_DIM + ak;
    const float* bp1 = We + (size_t)(n0 + 64 + ar) * IN_DIM + ak;

    float acc[4][8] = {};
    for (int kt = 0; kt < IN_DIM; kt += BK) {
        float4 av  = *(const float4*)(ap  + kt);
        float4 bv0 = *(const float4*)(bp0 + kt);
        float4 bv1 = *(const float4*)(bp1 + kt);
        __syncthreads();
        As2[ak+0][ar] = av.x;  As2[ak+1][ar] = av.y;  As2[ak+2][ar] = av.z;  As2[ak+3][ar] = av.w;
        Bs2[ak+0][ar] = bv0.x; Bs2[ak+1][ar] = bv0.y; Bs2[ak+2][ar] = bv0.z; Bs2[ak+3][ar] = bv0.w;
        Bs2[ak+0][ar+64] = bv1.x; Bs2[ak+1][ar+64] = bv1.y; Bs2[ak+2][ar+64] = bv1.z; Bs2[ak+3][ar+64] = bv1.w;
        __syncthreads();
        #pragma unroll
        for (int kk = 0; kk < BK; kk++) {
            float a_[4], b_[8];
            *(float4*)a_     = *(const float4*)&As2[kk][ty*4];
            *(float4*)b_     = *(const float4*)&Bs2[kk][tx*8];
            *(float4*)(b_+4) = *(const float4*)&Bs2[kk][tx*8+4];
            #pragma unroll
            for (int i = 0; i < 4; i++)
                #pragma unroll
                for (int j = 0; j < 8; j++)
                    acc[i][j] += a_[i] * b_[j];
        }
    }
    float be_[8];
    *(float4*)be_     = *(const float4*)&be[n0 + tx*8];
    *(float4*)(be_+4) = *(const float4*)&be[n0 + tx*8 + 4];
    #pragma unroll
    for (int i = 0; i < 4; i++) {
        float o[8];
        #pragma unroll
        for (int j = 0; j < 8; j++) {
            float v = acc[i][j] + be_[j];
            o[j] = v > 0.0f ? v : 0.0f;
        }
        float* dst = h + (size_t)(m0 + ty*4 + i) * HID + n0 + tx*8;
        *(float4*)dst     = *(const float4*)o;
        *(float4*)(dst+4) = *(const float4*)(o+4);
    }
}

__global__ __launch_bounds__(1024) void topk_mask(
    float* __restrict__ h, int* __restrict__ wIdx, float* __restrict__ wVal)
{
    const int row = blockIdx.x;
    const int tid = threadIdx.x;
    float* hrow = h + (size_t)row * HID;

    uint32_t u[32];
    #pragma unroll
    for (int i = 0; i < 32; i++)
        u[i] = __float_as_uint(hrow[tid + (i << 10)]);

    __shared__ int s_wave[16];
    __shared__ int s_total;
    __shared__ int s_cgt;
    __shared__ int s_ceq;
    __shared__ int s_keep;
    __shared__ int s_eq[64];

    uint32_t lo = 0;
    for (int bit = 30; bit >= 0; bit--) {
        uint32_t cand = lo | (1u << bit);
        int local = 0;
        #pragma unroll
        for (int i = 0; i < 32; i++) local += (u[i] >= cand) ? 1 : 0;
        #pragma unroll
        for (int off = 32; off > 0; off >>= 1) local += __shfl_down(local, off);
        if ((tid & 63) == 0) s_wave[tid >> 6] = local;
        __syncthreads();
        if (tid == 0) {
            int tot = 0;
            #pragma unroll
            for (int w = 0; w < 16; w++) tot += s_wave[w];
            s_total = tot;
        }
        __syncthreads();
        if (s_total >= TOPK) lo = cand;
        __syncthreads();
    }
    const uint32_t T = lo;

    if (tid == 0) { s_cgt = 0; s_ceq = 0; }
    __syncthreads();

    #pragma unroll
    for (int i = 0; i < 32; i++) {
        int idx = tid + (i << 10);
        if (u[i] > T) {
            int p = atomicAdd(&s_cgt, 1);
            wIdx[p * BATCH + row] = idx;
            wVal[p * BATCH + row] = __uint_as_float(u[i]);
        } else if (T != 0u && u[i] == T) {
            int p = atomicAdd(&s_ceq, 1);
            if (p < 64) s_eq[p] = idx;
        }
    }
    __syncthreads();

    if (tid == 0) {
        int c = s_cgt;
        int r = TOPK - c;
        if (T == 0u) {
            for (int q = 0; q < r; q++) {
                wIdx[(c + q) * BATCH + row] = 0;
                wVal[(c + q) * BATCH + row] = 0.0f;
            }
            s_keep = 0;
        } else {
            int e = s_ceq; if (e > 64) e = 64;
            for (int a2 = 1; a2 < e; a2++) {
                int key = s_eq[a2]; int b2 = a2 - 1;
                while (b2 >= 0 && s_eq[b2] > key) { s_eq[b2+1] = s_eq[b2]; b2--; }
                s_eq[b2+1] = key;
            }
            if (r > e) r = e;
            for (int q = 0; q < r; q++) {
                wIdx[(c + q) * BATCH + row] = s_eq[q];
                wVal[(c + q) * BATCH + row] = __uint_as_float(T);
            }
            for (int q = c + r; q < TOPK; q++) {
                wIdx[q * BATCH + row] = 0; wVal[q * BATCH + row] = 0.0f;
            }
            s_keep = r;
        }
    }
    __syncthreads();
    const int r2 = s_keep;

    #pragma unroll
    for (int i = 0; i < 32; i++) {
        int idx = tid + (i << 10);
        uint32_t uu = u[i];
        bool keep = uu > T;
        if (!keep && T != 0u && uu == T) {
            for (int q = 0; q < r2; q++) keep = keep || (s_eq[q] == idx);
        }
        hrow[idx] = keep ? __uint_as_float(uu) : 0.0f;
    }
}

#define DCHUNK 16384

__global__ __launch_bounds__(256) void decode_sparse(
    const float* __restrict__ Wd, const float* __restrict__ bd,
    const int* __restrict__ wIdx, const float* __restrict__ wVal,
    float* __restrict__ xhat)
{
    extern __shared__ float lds[];
    const int i = blockIdx.x;
    const int t = threadIdx.x;
    const float* wrow = Wd + (size_t)i * HID;
    const float bias = bd[i];
    float acc[8];
    #pragma unroll
    for (int q = 0; q < 8; q++) acc[q] = bias;

    for (int ch = 0; ch < HID / DCHUNK; ch++) {
        __syncthreads();
        const float4* src = (const float4*)(wrow + ch * DCHUNK);
        #pragma unroll
        for (int j = 0; j < DCHUNK / 4 / 256; j++)
            ((float4*)lds)[t + j * 256] = src[t + j * 256];
        __syncthreads();
        const uint32_t base = (uint32_t)(ch * DCHUNK);
        #pragma unroll
        for (int q = 0; q < 8; q++) {
            const int b = t + (q << 8);
            #pragma unroll 4
            for (int k = 0; k < TOPK; k++) {
                uint32_t off = (uint32_t)wIdx[(k << 11) + b] - base;
                if (off < (uint32_t)DCHUNK)
                    acc[q] += wVal[(k << 11) + b] * lds[off];
            }
        }
    }
    #pragma unroll
    for (int q = 0; q < 8; q++) {
        const int b = t + (q << 8);
        xhat[(size_t)b * IN_DIM + i] = acc[q];
    }
}

// =====================================================================
extern "C" void kernel_launch(void* const* d_in, const int* in_sizes, int n_in,
                              void* d_out, int out_size, void* d_ws, size_t ws_size,
                              hipStream_t stream)
{
    const float* x  = (const float*)d_in[0];
    const float* We = (const float*)d_in[1];
    const float* be = (const float*)d_in[2];
    const float* Wd = (const float*)d_in[3];
    const float* bd = (const float*)d_in[4];

    float* xhat = (float*)d_out;                               // [2048,1024]
    float* h    = (float*)d_out + (size_t)BATCH * IN_DIM;      // [2048,32768]

    const size_t MiB = 1ull << 20;
    // ws layout: xbf @0 (4 MiB), wbf @4 (64 MiB), wIdx/wVal @68 (512 KiB),
    // happ/WdT UNION @69 (128 MiB) — happ dies before transpose_wd runs.
    const size_t need = 197 * MiB;

    if (ws_size >= need) {
        ushort* xbf  = (ushort*)d_ws;
        ushort* wbf  = (ushort*)((char*)d_ws + 4 * MiB);
        int*    wIdx = (int*)   ((char*)d_ws + 68 * MiB);
        float*  wVal = (float*) ((char*)d_ws + 68 * MiB + 256 * 1024);
        ushort* happ = (ushort*)((char*)d_ws + 69 * MiB);
        float*  WdT  = (float*) ((char*)d_ws + 69 * MiB);

        to_bf16<<<(BATCH * IN_DIM / 4 + 255) / 256, 256, 0, stream>>>(x, xbf, BATCH * IN_DIM / 4);
        to_bf16<<<(HID * IN_DIM / 4 + 255) / 256, 256, 0, stream>>>(We, wbf, HID * IN_DIM / 4);
        encode_mfma<<<dim3(HID / 128, BATCH / 128), 256, 0, stream>>>(xbf, wbf, be, happ, h);
        topk_rerank<<<BATCH, 1024, 0, stream>>>(happ, h, x, We, be, wIdx, wVal);
        transpose_wd<<<dim3(HID / 64, IN_DIM / 64), 256, 0, stream>>>(Wd, WdT);
        decode_gather<<<BATCH, 256, 0, stream>>>(WdT, bd, wIdx, wVal, xhat);
    } else {
        int*   wIdx = (int*)d_ws;
        float* wVal = (float*)((char*)d_ws + sizeof(int) * BATCH * TOPK);
        dim3 g1(HID / BN, BATCH / BM);
        encode_gemm<<<g1, 256, 0, stream>>>(x, We, be, h);
        topk_mask<<<BATCH, 1024, 0, stream>>>(h, wIdx, wVal);
        decode_sparse<<<IN_DIM, 256, 65536, stream>>>(Wd, bd, wIdx, wVal, xhat);
    }
}